// Round 1
// baseline (688.927 us; speedup 1.0000x reference)
//
#include <hip/hip_runtime.h>
#include <hip/hip_bf16.h>

// Problem constants
#define N_TOKENS 8192
#define D_IN     2048
#define HIDDEN   2048
#define N_EXP    8
#define CAP      N_TOKENS   // worst-case tokens per expert (top-2)

typedef __bf16 bf16x8 __attribute__((ext_vector_type(8)));
typedef float  f32x4  __attribute__((ext_vector_type(4)));

// Workspace layout (bytes):
//   [0, 32)                cnt[8]           (zeroed per launch)
//   [4096, +8*CAP*4)       bucket_tok
//   [266240, +8*CAP*4)     bucket_w
//   [1<<20, +N*D*2)        x_bf16
//   [34603008, +E*D*H*2)   We_t  (bf16, [e][h][d])
#define OFF_CNT   0
#define OFF_TOK   4096
#define OFF_W     266240
#define OFF_XBF   1048576
#define OFF_WET   34603008

__device__ __forceinline__ unsigned short f2bf(float f) {
  unsigned int u = __builtin_bit_cast(unsigned int, f);
  u += 0x7fffu + ((u >> 16) & 1u);   // RNE (values are well-behaved, no NaN path)
  return (unsigned short)(u >> 16);
}

__device__ __forceinline__ void g2l16(const void* g, void* l) {
  // async global->LDS, 16B per lane; LDS dest must be wave-uniform base (+lane*16)
  __builtin_amdgcn_global_load_lds(
      (__attribute__((address_space(1))) void*)g,
      (__attribute__((address_space(3))) void*)l, 16, 0, 0);
}

// ---------------------------------------------------------------------------
// Kernel 1: gating (1 wave per token) + fused x fp32 -> bf16 conversion
// ---------------------------------------------------------------------------
__global__ __launch_bounds__(256) void gating_kernel(
    const float* __restrict__ x, const float* __restrict__ Wg,
    const float* __restrict__ bg, unsigned short* __restrict__ xbf,
    int* __restrict__ cnt, int* __restrict__ btok, float* __restrict__ bw)
{
  const int lane = threadIdx.x & 63;
  const int wid  = threadIdx.x >> 6;
  const int n    = blockIdx.x * 4 + wid;

  const float* xr = x + (size_t)n * D_IN;
  unsigned short* xbr = xbf + (size_t)n * D_IN;

  float acc[8];
#pragma unroll
  for (int e = 0; e < 8; ++e) acc[e] = 0.f;

#pragma unroll
  for (int c = 0; c < 8; ++c) {
    const int d = c * 256 + lane * 4;
    float4 xv = *(const float4*)(xr + d);
    uint2 pk;
    pk.x = (unsigned int)f2bf(xv.x) | ((unsigned int)f2bf(xv.y) << 16);
    pk.y = (unsigned int)f2bf(xv.z) | ((unsigned int)f2bf(xv.w) << 16);
    *(uint2*)(xbr + d) = pk;
    const float xs[4] = {xv.x, xv.y, xv.z, xv.w};
#pragma unroll
    for (int j = 0; j < 4; ++j) {
      const float4 w0 = *(const float4*)(Wg + (size_t)(d + j) * 8);
      const float4 w1 = *(const float4*)(Wg + (size_t)(d + j) * 8 + 4);
      acc[0] += xs[j] * w0.x; acc[1] += xs[j] * w0.y;
      acc[2] += xs[j] * w0.z; acc[3] += xs[j] * w0.w;
      acc[4] += xs[j] * w1.x; acc[5] += xs[j] * w1.y;
      acc[6] += xs[j] * w1.z; acc[7] += xs[j] * w1.w;
    }
  }

#pragma unroll
  for (int e = 0; e < 8; ++e) {
    float v = acc[e];
    v += __shfl_down(v, 32); v += __shfl_down(v, 16); v += __shfl_down(v, 8);
    v += __shfl_down(v, 4);  v += __shfl_down(v, 2);  v += __shfl_down(v, 1);
    acc[e] = v;
  }

  if (lane == 0) {
    float lg[8], p[8];
    float mx = -1e30f;
#pragma unroll
    for (int e = 0; e < 8; ++e) { lg[e] = acc[e] + bg[e]; mx = fmaxf(mx, lg[e]); }
    float s = 0.f;
#pragma unroll
    for (int e = 0; e < 8; ++e) { p[e] = expf(lg[e] - mx); s += p[e]; }
    const float inv = 1.f / s;
    // top-2 (strict > keeps lowest index on ties, matching jax.lax.top_k)
    int e1 = 0;
#pragma unroll
    for (int e = 1; e < 8; ++e) if (lg[e] > lg[e1]) e1 = e;
    int e2 = (e1 == 0) ? 1 : 0;
#pragma unroll
    for (int e = 0; e < 8; ++e) if (e != e1 && lg[e] > lg[e2]) e2 = e;

    const int s1 = atomicAdd(&cnt[e1], 1);
    btok[e1 * CAP + s1] = n;  bw[e1 * CAP + s1] = p[e1] * inv;
    const int s2 = atomicAdd(&cnt[e2], 1);
    btok[e2 * CAP + s2] = n;  bw[e2 * CAP + s2] = p[e2] * inv;
  }
}

// ---------------------------------------------------------------------------
// Kernel 2: We [e][d][h] fp32 -> We_t [e][h][d] bf16 (64x64 LDS tile transpose)
// ---------------------------------------------------------------------------
__global__ __launch_bounds__(256) void transpose_we(
    const float* __restrict__ We, unsigned short* __restrict__ wet)
{
  __shared__ float tile[64][68];  // 68: keep float4 rows 16B-aligned, break some conflicts
  const int e  = blockIdx.z;
  const int d0 = blockIdx.y * 64;
  const int h0 = blockIdx.x * 64;
  const int t  = threadIdx.x;
  const int r  = t >> 2;     // 0..63
  const int g  = t & 3;      // 0..3 (16-col group)

  const float* src = We + ((size_t)e * D_IN + d0 + r) * HIDDEN + h0 + g * 16;
#pragma unroll
  for (int i = 0; i < 4; ++i) {
    float4 v = *(const float4*)(src + i * 4);
    *(float4*)&tile[r][g * 16 + i * 4] = v;
  }
  __syncthreads();

  union { unsigned short s[16]; uint4 q[2]; } u;
#pragma unroll
  for (int i = 0; i < 16; ++i) u.s[i] = f2bf(tile[g * 16 + i][r]);
  uint4* dst = (uint4*)(wet + ((size_t)e * HIDDEN + h0 + r) * D_IN + d0 + g * 16);
  dst[0] = u.q[0];
  dst[1] = u.q[1];
}

// ---------------------------------------------------------------------------
// Kernel 3: grouped GEMM over expert buckets (128x128 tile, BK=64, bf16 MFMA)
// grid = (h_tiles=16, m_tiles=64, experts=8), 256 threads (4 waves, 2x2)
// ---------------------------------------------------------------------------
__global__ __launch_bounds__(256, 3) void moe_gemm(
    const unsigned short* __restrict__ xbf, const unsigned short* __restrict__ wet,
    const float* __restrict__ be, const int* __restrict__ cnt,
    const int* __restrict__ btok, const float* __restrict__ bw,
    float* __restrict__ out)
{
  const int e  = blockIdx.z;
  const int M  = cnt[e];
  const int m0 = blockIdx.y * 128;
  if (m0 >= M) return;
  const int h0 = blockIdx.x * 128;

  __shared__ __align__(16) unsigned short As[128 * 64];
  __shared__ __align__(16) unsigned short Bs[128 * 64];

  const int tid  = threadIdx.x;
  const int wid  = tid >> 6;
  const int lane = tid & 63;
  const int wm   = wid >> 1;   // 0..1
  const int wn   = wid & 1;    // 0..1

  const int* etok = btok + e * CAP;
  const float* ew = bw + e * CAP;

  // Per-thread staging sources (4 A chunks + 4 B chunks; base fixed, k0 advances)
  size_t asrc[4], bsrc[4];
#pragma unroll
  for (int j = 0; j < 4; ++j) {
    const int c = wid * 4 + j;               // chunk 0..15 (8 rows each)
    const int r = c * 8 + (lane >> 3);       // row within 128-tile
    int ar = m0 + r;
    if (ar >= M) ar = m0;                    // clamp to a valid row (discarded later)
    const int tok = etok[ar];
    asrc[j] = (size_t)tok * D_IN + (lane & 7) * 8;
    bsrc[j] = ((size_t)e * HIDDEN + h0 + r) * D_IN + (lane & 7) * 8;
  }

  f32x4 acc[4][4];
#pragma unroll
  for (int i = 0; i < 4; ++i)
#pragma unroll
    for (int j = 0; j < 4; ++j) acc[i][j] = (f32x4){0.f, 0.f, 0.f, 0.f};

  for (int k0 = 0; k0 < D_IN; k0 += 64) {
    __syncthreads();  // previous tile fully consumed
#pragma unroll
    for (int j = 0; j < 4; ++j)
      g2l16(xbf + asrc[j] + k0, &As[(wid * 4 + j) * 512]);
#pragma unroll
    for (int j = 0; j < 4; ++j)
      g2l16(wet + bsrc[j] + k0, &Bs[(wid * 4 + j) * 512]);
    __syncthreads();  // drains vmcnt: tile staged

#pragma unroll
    for (int kh = 0; kh < 2; ++kh) {
      bf16x8 af[4], bfr[4];
#pragma unroll
      for (int fm = 0; fm < 4; ++fm) {
        const int row = wm * 64 + fm * 16 + (lane & 15);
        af[fm] = __builtin_bit_cast(bf16x8,
            *(const uint4*)(As + row * 64 + kh * 32 + (lane >> 4) * 8));
      }
#pragma unroll
      for (int fn = 0; fn < 4; ++fn) {
        const int row = wn * 64 + fn * 16 + (lane & 15);
        bfr[fn] = __builtin_bit_cast(bf16x8,
            *(const uint4*)(Bs + row * 64 + kh * 32 + (lane >> 4) * 8));
      }
#pragma unroll
      for (int fm = 0; fm < 4; ++fm)
#pragma unroll
        for (int fn = 0; fn < 4; ++fn)
          acc[fm][fn] = __builtin_amdgcn_mfma_f32_16x16x32_bf16(
              af[fm], bfr[fn], acc[fm][fn], 0, 0, 0);
    }
  }

  // Epilogue: out[tok][h] += w * (acc + be[e][h]); C layout: col=lane&15, row=(lane>>4)*4+reg
  float bias[4];
#pragma unroll
  for (int fn = 0; fn < 4; ++fn)
    bias[fn] = be[e * HIDDEN + h0 + wn * 64 + fn * 16 + (lane & 15)];

#pragma unroll
  for (int fm = 0; fm < 4; ++fm) {
    const int rbase = m0 + wm * 64 + fm * 16 + (lane >> 4) * 4;
#pragma unroll
    for (int reg = 0; reg < 4; ++reg) {
      const int r = rbase + reg;
      if (r < M) {
        const int tok = etok[r];
        const float w = ew[r];
        float* orow = out + (size_t)tok * HIDDEN + h0 + wn * 64 + (lane & 15);
#pragma unroll
        for (int fn = 0; fn < 4; ++fn)
          atomicAdd(orow + fn * 16, w * (acc[fm][fn][reg] + bias[fn]));
      }
    }
  }
}

// ---------------------------------------------------------------------------
extern "C" void kernel_launch(void* const* d_in, const int* in_sizes, int n_in,
                              void* d_out, int out_size, void* d_ws, size_t ws_size,
                              hipStream_t stream) {
  const float* x  = (const float*)d_in[0];
  const float* Wg = (const float*)d_in[1];
  const float* bg = (const float*)d_in[2];
  const float* We = (const float*)d_in[3];
  const float* be = (const float*)d_in[4];
  float* out = (float*)d_out;

  char* ws = (char*)d_ws;
  int*            cnt  = (int*)(ws + OFF_CNT);
  int*            btok = (int*)(ws + OFF_TOK);
  float*          bw   = (float*)(ws + OFF_W);
  unsigned short* xbf  = (unsigned short*)(ws + OFF_XBF);
  unsigned short* wet  = (unsigned short*)(ws + OFF_WET);

  hipMemsetAsync(d_out, 0, (size_t)out_size * sizeof(float), stream);
  hipMemsetAsync(cnt, 0, N_EXP * sizeof(int), stream);

  gating_kernel<<<N_TOKENS / 4, 256, 0, stream>>>(x, Wg, bg, xbf, cnt, btok, bw);
  transpose_we<<<dim3(HIDDEN / 64, D_IN / 64, N_EXP), 256, 0, stream>>>(We, wet);
  moe_gemm<<<dim3(HIDDEN / 128, N_TOKENS / 128, N_EXP), 256, 0, stream>>>(
      xbf, wet, be, cnt, btok, bw, out);
}

// Round 2
// 532.321 us; speedup vs baseline: 1.2942x; 1.2942x over previous
//
#include <hip/hip_runtime.h>
#include <hip/hip_bf16.h>

// Problem constants
#define N_TOKENS 8192
#define D_IN     2048
#define HIDDEN   2048
#define N_EXP    8
#define CAP      N_TOKENS       // worst-case tokens per expert (top-2)
#define GATE_BLOCKS 256         // 32 tokens per block
#define TPOSE_BLOCKS (N_EXP * 32 * 32)  // 8192 (64x64 tiles)

typedef __bf16 bf16x8 __attribute__((ext_vector_type(8)));
typedef float  f32x4  __attribute__((ext_vector_type(4)));

// Workspace layout (bytes):
//   [0, 1024)              cnt[8*32]  (one counter per 128B line; zeroed per launch)
//   [4096, +8*CAP*4)       bucket_tok
//   [266240, +8*CAP*4)     bucket_w
//   [1<<20, +N*D*2)        x_bf16
//   [34603008, +E*D*H*2)   We_t  (bf16, [e][h][d])
#define OFF_CNT   0
#define OFF_TOK   4096
#define OFF_W     266240
#define OFF_XBF   1048576
#define OFF_WET   34603008

__device__ __forceinline__ unsigned short f2bf(float f) {
  unsigned int u = __builtin_bit_cast(unsigned int, f);
  u += 0x7fffu + ((u >> 16) & 1u);   // RNE
  return (unsigned short)(u >> 16);
}

__device__ __forceinline__ void g2l16(const void* g, void* l) {
  // async global->LDS, 16B/lane; LDS dest is wave-uniform base + lane*16
  __builtin_amdgcn_global_load_lds(
      (__attribute__((address_space(1))) void*)g,
      (__attribute__((address_space(3))) void*)l, 16, 0, 0);
}

// ---------------------------------------------------------------------------
// Fused prep kernel:
//   blocks [0, GATE_BLOCKS)                : gating + x fp32->bf16 conversion
//   blocks [GATE_BLOCKS, +TPOSE_BLOCKS)    : We [e][d][h] f32 -> We_t [e][h][d] bf16
// ---------------------------------------------------------------------------
union PrepSM {
  float tile[64][68];      // transpose path (17.4 KB)
  struct {
    int   lcnt[8];
    int   base[8];
    int   ltok[8][32];     // per-block, per-expert token lists (<=32 tokens/block)
    float lw[8][32];
  } g;
};

__global__ __launch_bounds__(256) void prep_kernel(
    const float* __restrict__ x, const float* __restrict__ Wg,
    const float* __restrict__ bg, const float* __restrict__ We,
    unsigned short* __restrict__ xbf, unsigned short* __restrict__ wet,
    int* __restrict__ cnt, int* __restrict__ btok, float* __restrict__ bw)
{
  __shared__ PrepSM sm;
  const int tid = threadIdx.x;

  if (blockIdx.x >= GATE_BLOCKS) {
    // ---------------- transpose + bf16 convert ----------------
    const int id = blockIdx.x - GATE_BLOCKS;
    const int e  = id >> 10;
    const int rem = id & 1023;
    const int d0 = (rem >> 5) << 6;
    const int h0 = (rem & 31) << 6;
    const int r  = tid >> 2;     // 0..63
    const int g  = tid & 3;      // 0..3

    const float* src = We + ((size_t)e * D_IN + d0 + r) * HIDDEN + h0 + g * 16;
#pragma unroll
    for (int i = 0; i < 4; ++i)
      *(float4*)&sm.tile[r][g * 16 + i * 4] = *(const float4*)(src + i * 4);
    __syncthreads();

    union { unsigned short s[16]; uint4 q[2]; } u;
#pragma unroll
    for (int i = 0; i < 16; ++i) u.s[i] = f2bf(sm.tile[g * 16 + i][r]);
    uint4* dst = (uint4*)(wet + ((size_t)e * HIDDEN + h0 + r) * D_IN + d0 + g * 16);
    dst[0] = u.q[0];
    dst[1] = u.q[1];
    return;
  }

  // ---------------- gating (32 tokens/block, 8/wave) ----------------
  const int lane = tid & 63;
  const int wid  = tid >> 6;
  if (tid < 8) sm.g.lcnt[tid] = 0;
  __syncthreads();

  const int tb = blockIdx.x * 32 + wid * 8;
  for (int tk = 0; tk < 8; ++tk) {
    const int n = tb + tk;
    const float* xr = x + (size_t)n * D_IN;
    unsigned short* xbr = xbf + (size_t)n * D_IN;

    // fused x -> bf16 (vectorized, coalesced)
#pragma unroll
    for (int c = 0; c < 8; ++c) {
      const int d = c * 256 + lane * 4;
      float4 xv = *(const float4*)(xr + d);
      uint2 pk;
      pk.x = (unsigned int)f2bf(xv.x) | ((unsigned int)f2bf(xv.y) << 16);
      pk.y = (unsigned int)f2bf(xv.z) | ((unsigned int)f2bf(xv.w) << 16);
      *(uint2*)(xbr + d) = pk;
    }

    // logits: 1 d per lane -> Wg row load is 32B/lane at 32B stride (16 lines/instr)
    float acc[8];
#pragma unroll
    for (int e = 0; e < 8; ++e) acc[e] = 0.f;
#pragma unroll 4
    for (int c = 0; c < 32; ++c) {
      const int d = c * 64 + lane;
      const float xv = xr[d];
      const float4 g0 = *(const float4*)(Wg + (size_t)d * 8);
      const float4 g1 = *(const float4*)(Wg + (size_t)d * 8 + 4);
      acc[0] += xv * g0.x; acc[1] += xv * g0.y;
      acc[2] += xv * g0.z; acc[3] += xv * g0.w;
      acc[4] += xv * g1.x; acc[5] += xv * g1.y;
      acc[6] += xv * g1.z; acc[7] += xv * g1.w;
    }
#pragma unroll
    for (int e = 0; e < 8; ++e) {
      float v = acc[e];
      v += __shfl_down(v, 32); v += __shfl_down(v, 16); v += __shfl_down(v, 8);
      v += __shfl_down(v, 4);  v += __shfl_down(v, 2);  v += __shfl_down(v, 1);
      acc[e] = v;
    }

    if (lane == 0) {
      float lg[8], p[8];
      float mx = -1e30f;
#pragma unroll
      for (int e = 0; e < 8; ++e) { lg[e] = acc[e] + bg[e]; mx = fmaxf(mx, lg[e]); }
      float s = 0.f;
#pragma unroll
      for (int e = 0; e < 8; ++e) { p[e] = expf(lg[e] - mx); s += p[e]; }
      const float inv = 1.f / s;
      int e1 = 0;
#pragma unroll
      for (int e = 1; e < 8; ++e) if (lg[e] > lg[e1]) e1 = e;
      int e2 = (e1 == 0) ? 1 : 0;
#pragma unroll
      for (int e = 0; e < 8; ++e) if (e != e1 && lg[e] > lg[e2]) e2 = e;

      const int s1 = atomicAdd(&sm.g.lcnt[e1], 1);
      sm.g.ltok[e1][s1] = n;  sm.g.lw[e1][s1] = p[e1] * inv;
      const int s2 = atomicAdd(&sm.g.lcnt[e2], 1);
      sm.g.ltok[e2][s2] = n;  sm.g.lw[e2][s2] = p[e2] * inv;
    }
  }
  __syncthreads();

  // one global atomic per expert per block (counters on separate 128B lines)
  if (tid < 8) sm.g.base[tid] = atomicAdd(&cnt[tid * 32], sm.g.lcnt[tid]);
  __syncthreads();

  const int e = tid >> 5, i = tid & 31;
  if (i < sm.g.lcnt[e]) {
    const int o = e * CAP + sm.g.base[e] + i;
    btok[o] = sm.g.ltok[e][i];
    bw[o]   = sm.g.lw[e][i];
  }
}

// ---------------------------------------------------------------------------
// Grouped GEMM over expert buckets (128x128 tile, BK=64, bf16 MFMA)
// grid = (h_tiles=16, m_tiles=64, experts=8), 256 threads (4 waves, 2x2)
// LDS tiles XOR-swizzled (kc ^= row&7) to kill 16-way bank conflicts.
// ---------------------------------------------------------------------------
__global__ __launch_bounds__(256, 4) void moe_gemm(
    const unsigned short* __restrict__ xbf, const unsigned short* __restrict__ wet,
    const float* __restrict__ be, const int* __restrict__ cnt,
    const int* __restrict__ btok, const float* __restrict__ bw,
    float* __restrict__ out)
{
  const int e  = blockIdx.z;
  const int M  = cnt[e * 32];
  const int m0 = blockIdx.y * 128;
  if (m0 >= M) return;
  const int h0 = blockIdx.x * 128;

  __shared__ __align__(16) unsigned short As[128 * 64];
  __shared__ __align__(16) unsigned short Bs[128 * 64];

  const int tid  = threadIdx.x;
  const int wid  = tid >> 6;
  const int lane = tid & 63;
  const int wm   = wid >> 1;   // 0..1
  const int wn   = wid & 1;    // 0..1

  const int* etok = btok + e * CAP;
  const float* ew = bw + e * CAP;

  // swizzled per-lane source column: data for k-chunk (c ^ localrow) goes at lane pos c
  const int kcs = (((lane & 7) ^ (lane >> 3)) * 8);

  size_t asrc[4], bsrc[4];
#pragma unroll
  for (int j = 0; j < 4; ++j) {
    const int c = wid * 4 + j;               // chunk 0..15 (8 rows each)
    const int r = c * 8 + (lane >> 3);       // row within 128-tile
    int ar = m0 + r;
    if (ar >= M) ar = m0;                    // clamp (discarded in epilogue)
    const int tok = etok[ar];
    asrc[j] = (size_t)tok * D_IN + kcs;
    bsrc[j] = ((size_t)e * HIDDEN + h0 + r) * D_IN + kcs;
  }

  f32x4 acc[4][4];
#pragma unroll
  for (int i = 0; i < 4; ++i)
#pragma unroll
    for (int j = 0; j < 4; ++j) acc[i][j] = (f32x4){0.f, 0.f, 0.f, 0.f};

  for (int k0 = 0; k0 < D_IN; k0 += 64) {
    __syncthreads();  // previous tile fully consumed
#pragma unroll
    for (int j = 0; j < 4; ++j)
      g2l16(xbf + asrc[j] + k0, &As[(wid * 4 + j) * 512]);
#pragma unroll
    for (int j = 0; j < 4; ++j)
      g2l16(wet + bsrc[j] + k0, &Bs[(wid * 4 + j) * 512]);
    __syncthreads();  // tile staged

#pragma unroll
    for (int kh = 0; kh < 2; ++kh) {
      bf16x8 af[4], bfr[4];
#pragma unroll
      for (int fm = 0; fm < 4; ++fm) {
        const int row = wm * 64 + fm * 16 + (lane & 15);
        const int kc  = kh * 4 + (lane >> 4);
        af[fm] = __builtin_bit_cast(bf16x8,
            *(const uint4*)(As + row * 64 + ((kc ^ (row & 7)) * 8)));
      }
#pragma unroll
      for (int fn = 0; fn < 4; ++fn) {
        const int row = wn * 64 + fn * 16 + (lane & 15);
        const int kc  = kh * 4 + (lane >> 4);
        bfr[fn] = __builtin_bit_cast(bf16x8,
            *(const uint4*)(Bs + row * 64 + ((kc ^ (row & 7)) * 8)));
      }
#pragma unroll
      for (int fm = 0; fm < 4; ++fm)
#pragma unroll
        for (int fn = 0; fn < 4; ++fn)
          acc[fm][fn] = __builtin_amdgcn_mfma_f32_16x16x32_bf16(
              af[fm], bfr[fn], acc[fm][fn], 0, 0, 0);
    }
  }

  // Epilogue: out[tok][h] += w * (acc + be[e][h]); C layout: col=lane&15, row=(lane>>4)*4+reg
  float bias[4];
#pragma unroll
  for (int fn = 0; fn < 4; ++fn)
    bias[fn] = be[e * HIDDEN + h0 + wn * 64 + fn * 16 + (lane & 15)];

#pragma unroll
  for (int fm = 0; fm < 4; ++fm) {
    const int rbase = m0 + wm * 64 + fm * 16 + (lane >> 4) * 4;
#pragma unroll
    for (int reg = 0; reg < 4; ++reg) {
      const int r = rbase + reg;
      if (r < M) {
        const int tok = etok[r];
        const float w = ew[r];
        float* orow = out + (size_t)tok * HIDDEN + h0 + wn * 64 + (lane & 15);
#pragma unroll
        for (int fn = 0; fn < 4; ++fn)
          atomicAdd(orow + fn * 16, w * (acc[fm][fn][reg] + bias[fn]));
      }
    }
  }
}

// ---------------------------------------------------------------------------
extern "C" void kernel_launch(void* const* d_in, const int* in_sizes, int n_in,
                              void* d_out, int out_size, void* d_ws, size_t ws_size,
                              hipStream_t stream) {
  const float* x  = (const float*)d_in[0];
  const float* Wg = (const float*)d_in[1];
  const float* bg = (const float*)d_in[2];
  const float* We = (const float*)d_in[3];
  const float* be = (const float*)d_in[4];
  float* out = (float*)d_out;

  char* ws = (char*)d_ws;
  int*            cnt  = (int*)(ws + OFF_CNT);
  int*            btok = (int*)(ws + OFF_TOK);
  float*          bw   = (float*)(ws + OFF_W);
  unsigned short* xbf  = (unsigned short*)(ws + OFF_XBF);
  unsigned short* wet  = (unsigned short*)(ws + OFF_WET);

  hipMemsetAsync(d_out, 0, (size_t)out_size * sizeof(float), stream);
  hipMemsetAsync(cnt, 0, 8 * 32 * sizeof(int), stream);

  prep_kernel<<<GATE_BLOCKS + TPOSE_BLOCKS, 256, 0, stream>>>(
      x, Wg, bg, We, xbf, wet, cnt, btok, bw);
  moe_gemm<<<dim3(HIDDEN / 128, N_TOKENS / 128, N_EXP), 256, 0, stream>>>(
      xbf, wet, be, cnt, btok, bw, out);
}